// Round 1
// baseline (717.585 us; speedup 1.0000x reference)
//
#include <hip/hip_runtime.h>
#include <math.h>

#define N_TOK 16384
#define DIM   768
#define FFD   3072
#define NEXP  8
#define EPSV  1e-6f

typedef __attribute__((ext_vector_type(4))) float f32x4;
typedef __attribute__((ext_vector_type(8))) unsigned short u16x8;
typedef __attribute__((ext_vector_type(8))) __bf16 bf16x8;

static __device__ __forceinline__ unsigned short f2bf(float f) {
    unsigned int u = __builtin_bit_cast(unsigned int, f);
    u += 0x7fffu + ((u >> 16) & 1u);   // round-to-nearest-even
    return (unsigned short)(u >> 16);
}
static __device__ __forceinline__ bf16x8 as_bf(u16x8 v) {
    return __builtin_bit_cast(bf16x8, v);
}

// ---------------------------------------------------------------------------
// Kernel 1: RMSNorm + router (f32) + argmax + compaction. One block per token.
// ---------------------------------------------------------------------------
__global__ __launch_bounds__(256) void k_norm_router(
    const float* __restrict__ x, const float* __restrict__ lnw,
    const float* __restrict__ rw,
    float* __restrict__ out_logits, float* __restrict__ out_eidx,
    float* __restrict__ topp, int* __restrict__ list, int* __restrict__ cnt,
    unsigned short* __restrict__ xn)
{
    __shared__ float sbuf[256];
    __shared__ float rbuf[8 * 256];
    const int i = blockIdx.x;
    const int t = threadIdx.x;
    const size_t base = (size_t)i * DIM;

    float v0 = x[base + t], v1 = x[base + t + 256], v2 = x[base + t + 512];
    sbuf[t] = v0 * v0 + v1 * v1 + v2 * v2;
    __syncthreads();
    for (int s = 128; s > 0; s >>= 1) {
        if (t < s) sbuf[t] += sbuf[t + s];
        __syncthreads();
    }
    const float rstd = rsqrtf(sbuf[0] / (float)DIM + EPSV);

    float xv0 = v0 * rstd * lnw[t];
    float xv1 = v1 * rstd * lnw[t + 256];
    float xv2 = v2 * rstd * lnw[t + 512];
    xn[base + t]       = f2bf(xv0);
    xn[base + t + 256] = f2bf(xv1);
    xn[base + t + 512] = f2bf(xv2);

    float rp[8];
#pragma unroll
    for (int e = 0; e < 8; e++) rp[e] = 0.f;
#pragma unroll
    for (int q = 0; q < 3; q++) {
        int d = t + q * 256;
        float xv = (q == 0) ? xv0 : ((q == 1) ? xv1 : xv2);
        const float4* rwp = (const float4*)(rw + (size_t)d * 8);
        float4 r0 = rwp[0], r1 = rwp[1];
        rp[0] += xv * r0.x; rp[1] += xv * r0.y; rp[2] += xv * r0.z; rp[3] += xv * r0.w;
        rp[4] += xv * r1.x; rp[5] += xv * r1.y; rp[6] += xv * r1.z; rp[7] += xv * r1.w;
    }
#pragma unroll
    for (int e = 0; e < 8; e++) rbuf[e * 256 + t] = rp[e];
    __syncthreads();
    for (int s = 128; s > 0; s >>= 1) {
        if (t < s) {
#pragma unroll
            for (int e = 0; e < 8; e++) rbuf[e * 256 + t] += rbuf[e * 256 + t + s];
        }
        __syncthreads();
    }
    if (t == 0) {
        float lg[8];
        float m = -1e30f; int am = 0;
#pragma unroll
        for (int e = 0; e < 8; e++) {
            lg[e] = rbuf[e * 256];
            out_logits[(size_t)i * 8 + e] = lg[e];
        }
#pragma unroll
        for (int e = 0; e < 8; e++) {
            if (lg[e] > m) { m = lg[e]; am = e; }
        }
        float se = 0.f;
#pragma unroll
        for (int e = 0; e < 8; e++) se += expf(lg[e] - m);
        topp[i] = 1.0f / se;          // max prob = exp(0)/sum
        out_eidx[i] = (float)am;
        int pos = atomicAdd(&cnt[am], 1);
        list[am * N_TOK + pos] = i;
    }
}

// ---------------------------------------------------------------------------
// Kernel 2: grouped GEMM1  H[tok, :] = relu( Xn[tok, :] @ Wi[e] )   (bf16 out)
// 64x64 tile, BK=64, 4 waves (2x2), MFMA 16x16x32 bf16.
// ---------------------------------------------------------------------------
__global__ __launch_bounds__(256) void k_ffn1(
    const unsigned short* __restrict__ xn, const float* __restrict__ wi,
    const int* __restrict__ list, const int* __restrict__ cnt,
    unsigned short* __restrict__ Hb)
{
    __shared__ unsigned short Asm[64][72];
    __shared__ unsigned short Bsm[64][72];   // [n][k]
    __shared__ int tokrow[64];
    __shared__ int spref[9];

    const int t = threadIdx.x;
    const int lane = t & 63, wid = t >> 6;
    if (t == 0) {
        int p = 0; spref[0] = 0;
        for (int e = 0; e < 8; e++) { p += (cnt[e] + 63) >> 6; spref[e + 1] = p; }
    }
    __syncthreads();
    const int TN = FFD / 64;               // 48
    const int total = spref[8] * TN;
    const int moff = (wid >> 1) * 32, noff = (wid & 1) * 32;
    const int lr = lane & 15, lk = (lane >> 4) * 8, lq = lane >> 4;
    const int row = t >> 2, kc = (t & 3) << 4;

    for (int w = blockIdx.x; w < total; w += gridDim.x) {
        const int gm = w / TN, tn = w - gm * TN;
        int e = 0;
        while (gm >= spref[e + 1]) e++;
        const int ce = cnt[e];
        const int m0 = (gm - spref[e]) * 64, n0 = tn * 64;

        __syncthreads();
        if (t < 64) { int m = m0 + t; tokrow[t] = (m < ce) ? list[e * N_TOK + m] : -1; }
        __syncthreads();

        f32x4 acc00 = {0,0,0,0}, acc01 = {0,0,0,0}, acc10 = {0,0,0,0}, acc11 = {0,0,0,0};

        for (int k0 = 0; k0 < DIM; k0 += 64) {
            // stage A (gathered bf16 rows): 16 bf16 per thread
            int tok = tokrow[row];
            uint4 q0 = {0,0,0,0}, q1 = {0,0,0,0};
            if (tok >= 0) {
                const uint4* p = (const uint4*)(xn + (size_t)tok * DIM + k0 + kc);
                q0 = p[0]; q1 = p[1];
            }
            *(uint4*)&Asm[row][kc]     = q0;
            *(uint4*)&Asm[row][kc + 8] = q1;
            // stage B (f32 -> bf16, transposed to [n][k]): k = row, n = kc..kc+15
            const float* wp = wi + ((size_t)e * DIM + k0 + row) * FFD + n0 + kc;
#pragma unroll
            for (int j = 0; j < 16; j += 4) {
                float4 f = *(const float4*)(wp + j);
                Bsm[kc + j + 0][row] = f2bf(f.x);
                Bsm[kc + j + 1][row] = f2bf(f.y);
                Bsm[kc + j + 2][row] = f2bf(f.z);
                Bsm[kc + j + 3][row] = f2bf(f.w);
            }
            __syncthreads();
#pragma unroll
            for (int kf = 0; kf < 2; kf++) {
                bf16x8 a0 = as_bf(*(const u16x8*)&Asm[moff + lr][kf * 32 + lk]);
                bf16x8 a1 = as_bf(*(const u16x8*)&Asm[moff + 16 + lr][kf * 32 + lk]);
                bf16x8 b0 = as_bf(*(const u16x8*)&Bsm[noff + lr][kf * 32 + lk]);
                bf16x8 b1 = as_bf(*(const u16x8*)&Bsm[noff + 16 + lr][kf * 32 + lk]);
                acc00 = __builtin_amdgcn_mfma_f32_16x16x32_bf16(a0, b0, acc00, 0, 0, 0);
                acc01 = __builtin_amdgcn_mfma_f32_16x16x32_bf16(a0, b1, acc01, 0, 0, 0);
                acc10 = __builtin_amdgcn_mfma_f32_16x16x32_bf16(a1, b0, acc10, 0, 0, 0);
                acc11 = __builtin_amdgcn_mfma_f32_16x16x32_bf16(a1, b1, acc11, 0, 0, 0);
            }
            __syncthreads();
        }
        // epilogue: relu -> bf16 H
#pragma unroll
        for (int mi = 0; mi < 2; mi++) {
#pragma unroll
            for (int ni = 0; ni < 2; ni++) {
                f32x4 a = (mi == 0) ? ((ni == 0) ? acc00 : acc01)
                                    : ((ni == 0) ? acc10 : acc11);
#pragma unroll
                for (int r = 0; r < 4; r++) {
                    int rr = moff + mi * 16 + lq * 4 + r;
                    int tok = tokrow[rr];
                    if (tok >= 0) {
                        float v = a[r]; v = v > 0.f ? v : 0.f;
                        Hb[(size_t)tok * FFD + n0 + noff + ni * 16 + lr] = f2bf(v);
                    }
                }
            }
        }
    }
}

// ---------------------------------------------------------------------------
// Kernel 3: grouped GEMM2  out[tok,:] = hidden[tok,:] + topp[tok]*(H[tok,:] @ Wo[e])
// ---------------------------------------------------------------------------
__global__ __launch_bounds__(256) void k_ffn2(
    const unsigned short* __restrict__ Hb, const float* __restrict__ wo,
    const int* __restrict__ list, const int* __restrict__ cnt,
    const float* __restrict__ hs, const float* __restrict__ topp,
    float* __restrict__ out)
{
    __shared__ unsigned short Asm[64][72];
    __shared__ unsigned short Bsm[64][72];   // [n][k]
    __shared__ int tokrow[64];
    __shared__ int spref[9];

    const int t = threadIdx.x;
    const int lane = t & 63, wid = t >> 6;
    if (t == 0) {
        int p = 0; spref[0] = 0;
        for (int e = 0; e < 8; e++) { p += (cnt[e] + 63) >> 6; spref[e + 1] = p; }
    }
    __syncthreads();
    const int TN = DIM / 64;               // 12
    const int total = spref[8] * TN;
    const int moff = (wid >> 1) * 32, noff = (wid & 1) * 32;
    const int lr = lane & 15, lk = (lane >> 4) * 8, lq = lane >> 4;
    const int row = t >> 2, kc = (t & 3) << 4;

    for (int w = blockIdx.x; w < total; w += gridDim.x) {
        const int gm = w / TN, tn = w - gm * TN;
        int e = 0;
        while (gm >= spref[e + 1]) e++;
        const int ce = cnt[e];
        const int m0 = (gm - spref[e]) * 64, n0 = tn * 64;

        __syncthreads();
        if (t < 64) { int m = m0 + t; tokrow[t] = (m < ce) ? list[e * N_TOK + m] : -1; }
        __syncthreads();

        f32x4 acc00 = {0,0,0,0}, acc01 = {0,0,0,0}, acc10 = {0,0,0,0}, acc11 = {0,0,0,0};

        for (int k0 = 0; k0 < FFD; k0 += 64) {
            int tok = tokrow[row];
            uint4 q0 = {0,0,0,0}, q1 = {0,0,0,0};
            if (tok >= 0) {
                const uint4* p = (const uint4*)(Hb + (size_t)tok * FFD + k0 + kc);
                q0 = p[0]; q1 = p[1];
            }
            *(uint4*)&Asm[row][kc]     = q0;
            *(uint4*)&Asm[row][kc + 8] = q1;
            const float* wp = wo + ((size_t)e * FFD + k0 + row) * DIM + n0 + kc;
#pragma unroll
            for (int j = 0; j < 16; j += 4) {
                float4 f = *(const float4*)(wp + j);
                Bsm[kc + j + 0][row] = f2bf(f.x);
                Bsm[kc + j + 1][row] = f2bf(f.y);
                Bsm[kc + j + 2][row] = f2bf(f.z);
                Bsm[kc + j + 3][row] = f2bf(f.w);
            }
            __syncthreads();
#pragma unroll
            for (int kf = 0; kf < 2; kf++) {
                bf16x8 a0 = as_bf(*(const u16x8*)&Asm[moff + lr][kf * 32 + lk]);
                bf16x8 a1 = as_bf(*(const u16x8*)&Asm[moff + 16 + lr][kf * 32 + lk]);
                bf16x8 b0 = as_bf(*(const u16x8*)&Bsm[noff + lr][kf * 32 + lk]);
                bf16x8 b1 = as_bf(*(const u16x8*)&Bsm[noff + 16 + lr][kf * 32 + lk]);
                acc00 = __builtin_amdgcn_mfma_f32_16x16x32_bf16(a0, b0, acc00, 0, 0, 0);
                acc01 = __builtin_amdgcn_mfma_f32_16x16x32_bf16(a0, b1, acc01, 0, 0, 0);
                acc10 = __builtin_amdgcn_mfma_f32_16x16x32_bf16(a1, b0, acc10, 0, 0, 0);
                acc11 = __builtin_amdgcn_mfma_f32_16x16x32_bf16(a1, b1, acc11, 0, 0, 0);
            }
            __syncthreads();
        }
#pragma unroll
        for (int mi = 0; mi < 2; mi++) {
#pragma unroll
            for (int ni = 0; ni < 2; ni++) {
                f32x4 a = (mi == 0) ? ((ni == 0) ? acc00 : acc01)
                                    : ((ni == 0) ? acc10 : acc11);
#pragma unroll
                for (int r = 0; r < 4; r++) {
                    int rr = moff + mi * 16 + lq * 4 + r;
                    int tok = tokrow[rr];
                    if (tok >= 0) {
                        int col = n0 + noff + ni * 16 + lr;
                        size_t idx = (size_t)tok * DIM + col;
                        out[idx] = hs[idx] + topp[tok] * a[r];
                    }
                }
            }
        }
    }
}

// ---------------------------------------------------------------------------
extern "C" void kernel_launch(void* const* d_in, const int* in_sizes, int n_in,
                              void* d_out, int out_size, void* d_ws, size_t ws_size,
                              hipStream_t stream)
{
    const float* hs  = (const float*)d_in[0];
    const float* lnw = (const float*)d_in[1];
    const float* rw  = (const float*)d_in[2];
    const float* wi  = (const float*)d_in[3];
    const float* wo  = (const float*)d_in[4];

    float* out        = (float*)d_out;
    float* out_logits = out + (size_t)N_TOK * DIM;
    float* out_eidx   = out_logits + (size_t)N_TOK * NEXP;

    char* ws = (char*)d_ws;
    int*   cnt  = (int*)ws;                                          // 32 B (+pad to 256)
    int*   list = (int*)(ws + 256);                                  // 8*16384*4 = 512 KiB
    float* topp = (float*)(ws + 256 + (size_t)NEXP * N_TOK * 4);     // 64 KiB
    unsigned short* xn = (unsigned short*)(ws + 256 + (size_t)NEXP * N_TOK * 4 + (size_t)N_TOK * 4);
    unsigned short* Hb = xn + (size_t)N_TOK * DIM;                   // 100 MiB bf16

    hipMemsetAsync(cnt, 0, NEXP * sizeof(int), stream);
    k_norm_router<<<N_TOK, 256, 0, stream>>>(hs, lnw, rw, out_logits, out_eidx,
                                             topp, list, cnt, xn);
    k_ffn1<<<12624, 256, 0, stream>>>(xn, wi, list, cnt, Hb);
    k_ffn2<<<3156,  256, 0, stream>>>(Hb, wo, list, cnt, hs, topp, out);
}

// Round 2
// 522.734 us; speedup vs baseline: 1.3728x; 1.3728x over previous
//
#include <hip/hip_runtime.h>
#include <math.h>

#define N_TOK 16384
#define DIM   768
#define FFD   3072
#define NEXP  8
#define EPSV  1e-6f

typedef __attribute__((ext_vector_type(4))) float f32x4;
typedef __attribute__((ext_vector_type(4))) unsigned short u16x4;
typedef __attribute__((ext_vector_type(8))) unsigned short u16x8;
typedef __attribute__((ext_vector_type(8))) __bf16 bf16x8;

static __device__ __forceinline__ unsigned short f2bf(float f) {
    unsigned int u = __builtin_bit_cast(unsigned int, f);
    u += 0x7fffu + ((u >> 16) & 1u);   // round-to-nearest-even
    return (unsigned short)(u >> 16);
}
static __device__ __forceinline__ bf16x8 as_bf(u16x8 v) {
    return __builtin_bit_cast(bf16x8, v);
}
static __device__ __forceinline__ void gload16(const void* g, void* l) {
    __builtin_amdgcn_global_load_lds(
        (const __attribute__((address_space(1))) unsigned int*)g,
        (__attribute__((address_space(3))) unsigned int*)l, 16, 0, 0);
}

// ---------------------------------------------------------------------------
// Kernel 0: convert+transpose  in[e][R][C] f32  ->  out[e][C][R] bf16
// 64x64 tiles, 256 threads.
// ---------------------------------------------------------------------------
__global__ __launch_bounds__(256) void k_convT(
    const float* __restrict__ in, unsigned short* __restrict__ outp,
    int R, int C)
{
    __shared__ float tile[64][68];     // stride 68 f32: 16B-aligned rows, 2-way col reads
    const int bc = C >> 6, br = R >> 6;
    const int b = blockIdx.x;
    const int e = b / (bc * br);
    const int rem = b - e * bc * br;
    const int rt = rem / bc, ct = rem - rt * bc;
    const int t = threadIdx.x;
    {
        const int r = t >> 2, c4 = (t & 3) << 4;
        const float* src = in + ((size_t)e * R + rt * 64 + r) * C + ct * 64 + c4;
#pragma unroll
        for (int q = 0; q < 4; q++) {
            float4 f = ((const float4*)src)[q];
            tile[r][c4 + q * 4 + 0] = f.x;
            tile[r][c4 + q * 4 + 1] = f.y;
            tile[r][c4 + q * 4 + 2] = f.z;
            tile[r][c4 + q * 4 + 3] = f.w;
        }
    }
    __syncthreads();
    {
        const int c = t >> 2, r4 = (t & 3) << 4;
        u16x8 o0, o1;
#pragma unroll
        for (int j = 0; j < 8; j++)  o0[j] = f2bf(tile[r4 + j][c]);
#pragma unroll
        for (int j = 0; j < 8; j++)  o1[j] = f2bf(tile[r4 + 8 + j][c]);
        unsigned short* dst = outp + ((size_t)e * C + ct * 64 + c) * R + rt * 64 + r4;
        *(u16x8*)dst       = o0;
        *(u16x8*)(dst + 8) = o1;
    }
}

// ---------------------------------------------------------------------------
// Kernel 1: RMSNorm + router, one wave per token.
// ---------------------------------------------------------------------------
__global__ __launch_bounds__(256) void k_router(
    const float* __restrict__ x, const float* __restrict__ lnw,
    const float* __restrict__ rw,
    float* __restrict__ out_logits, float* __restrict__ out_eidx,
    float* __restrict__ topp, int* __restrict__ list, int* __restrict__ cnt,
    unsigned short* __restrict__ xn)
{
    const int wid = threadIdx.x >> 6, lane = threadIdx.x & 63;
    const int tok = blockIdx.x * 4 + wid;
    const size_t base = (size_t)tok * DIM;

    float4 v[3];
#pragma unroll
    for (int j = 0; j < 3; j++)
        v[j] = *(const float4*)(x + base + lane * 4 + j * 256);
    float ss = 0.f;
#pragma unroll
    for (int j = 0; j < 3; j++)
        ss += v[j].x * v[j].x + v[j].y * v[j].y + v[j].z * v[j].z + v[j].w * v[j].w;
#pragma unroll
    for (int s = 32; s > 0; s >>= 1) ss += __shfl_xor(ss, s);
    const float rstd = rsqrtf(ss * (1.0f / DIM) + EPSV);

    float rp[8];
#pragma unroll
    for (int e = 0; e < 8; e++) rp[e] = 0.f;
#pragma unroll
    for (int j = 0; j < 3; j++) {
        float4 lw = *(const float4*)(lnw + lane * 4 + j * 256);
        float xv[4] = { v[j].x * rstd * lw.x, v[j].y * rstd * lw.y,
                        v[j].z * rstd * lw.z, v[j].w * rstd * lw.w };
        u16x4 pk = { f2bf(xv[0]), f2bf(xv[1]), f2bf(xv[2]), f2bf(xv[3]) };
        *(u16x4*)(xn + base + lane * 4 + j * 256) = pk;
#pragma unroll
        for (int i = 0; i < 4; i++) {
            const int d = lane * 4 + j * 256 + i;
            const float4* rr = (const float4*)(rw + (size_t)d * 8);
            float4 a = rr[0], bq = rr[1];
            rp[0] += xv[i] * a.x;  rp[1] += xv[i] * a.y;
            rp[2] += xv[i] * a.z;  rp[3] += xv[i] * a.w;
            rp[4] += xv[i] * bq.x; rp[5] += xv[i] * bq.y;
            rp[6] += xv[i] * bq.z; rp[7] += xv[i] * bq.w;
        }
    }
#pragma unroll
    for (int s = 32; s > 0; s >>= 1) {
#pragma unroll
        for (int e = 0; e < 8; e++) rp[e] += __shfl_xor(rp[e], s);
    }
    if (lane == 0) {
        float m = -1e30f; int am = 0;
#pragma unroll
        for (int e = 0; e < 8; e++) {
            out_logits[(size_t)tok * 8 + e] = rp[e];
            if (rp[e] > m) { m = rp[e]; am = e; }
        }
        float se = 0.f;
#pragma unroll
        for (int e = 0; e < 8; e++) se += expf(rp[e] - m);
        topp[tok] = 1.0f / se;
        out_eidx[tok] = (float)am;
        int pos = atomicAdd(&cnt[am], 1);
        list[am * N_TOK + pos] = tok;
    }
}

// ---------------------------------------------------------------------------
// Grouped GEMM, m97 structure: 128x128 tile, BK=64, 4 waves (2x2 of 64x64),
// global_load_lds 16B staging, XOR chunk swizzle (source-side + read-side).
// MODE 0: H = relu(Xn @ WiT)   MODE 1: out = hs + topp*(H @ WoT)
// ---------------------------------------------------------------------------
template<int MODE>
__global__ __launch_bounds__(256) void k_gemm(
    const unsigned short* __restrict__ A, const unsigned short* __restrict__ Bw,
    const int* __restrict__ list, const int* __restrict__ cnt,
    unsigned short* __restrict__ Hout,
    const float* __restrict__ hs, const float* __restrict__ topp,
    float* __restrict__ out)
{
    constexpr int K   = (MODE == 0) ? DIM : FFD;
    constexpr int N   = (MODE == 0) ? FFD : DIM;
    constexpr int TNT = N / 128;
    __shared__ unsigned short Asm[128 * 64];
    __shared__ unsigned short Bsm[128 * 64];
    __shared__ int tokrow[128];
    __shared__ int spref[9];

    const int t = threadIdx.x, lane = t & 63, wid = t >> 6;
    if (t == 0) {
        int p = 0; spref[0] = 0;
        for (int e = 0; e < 8; e++) { p += (cnt[e] + 127) >> 7; spref[e + 1] = p; }
    }
    __syncthreads();
    const int total = spref[8] * TNT;
    const int moff = (wid >> 1) * 64, noff = (wid & 1) * 64;
    const int lr = lane & 15, lq = lane >> 4;

    // chunk geometry: chunk c = (wid*4+i)*64+lane; row=c>>3; sub=(c&7)^(row&7)
    int crow[4], csub[4];
#pragma unroll
    for (int i = 0; i < 4; i++) {
        int c = (wid * 4 + i) * 64 + lane;
        crow[i] = c >> 3;
        csub[i] = (c & 7) ^ (crow[i] & 7);
    }

    for (int w = blockIdx.x; w < total; w += gridDim.x) {
        const int gm = w / TNT, tn = w - gm * TNT;
        int e = 0;
        while (gm >= spref[e + 1]) e++;
        const int ce = cnt[e];
        const int m0 = (gm - spref[e]) * 128, n0 = tn * 128;

        __syncthreads();
        if (t < 128) {
            int m = m0 + t;
            tokrow[t] = (m < ce) ? list[e * N_TOK + m] : list[e * N_TOK];
        }
        __syncthreads();

        const unsigned short* aP[4];
        const unsigned short* bP[4];
#pragma unroll
        for (int i = 0; i < 4; i++) {
            aP[i] = A + (size_t)tokrow[crow[i]] * K + csub[i] * 8;
            bP[i] = Bw + ((size_t)e * N + n0 + crow[i]) * K + csub[i] * 8;
        }

        f32x4 acc[4][4];
#pragma unroll
        for (int mi = 0; mi < 4; mi++)
#pragma unroll
            for (int ni = 0; ni < 4; ni++) acc[mi][ni] = (f32x4){0, 0, 0, 0};

        for (int k0 = 0; k0 < K; k0 += 64) {
#pragma unroll
            for (int i = 0; i < 4; i++) {
                gload16(aP[i] + k0, Asm + (wid * 4 + i) * 512);
                gload16(bP[i] + k0, Bsm + (wid * 4 + i) * 512);
            }
            __syncthreads();
#pragma unroll
            for (int kf = 0; kf < 2; kf++) {
                const int phys = ((kf * 4 + lq) ^ (lr & 7)) * 8;
                bf16x8 af[4], bfr[4];
#pragma unroll
                for (int mi = 0; mi < 4; mi++)
                    af[mi] = as_bf(*(const u16x8*)&Asm[(moff + mi * 16 + lr) * 64 + phys]);
#pragma unroll
                for (int ni = 0; ni < 4; ni++)
                    bfr[ni] = as_bf(*(const u16x8*)&Bsm[(noff + ni * 16 + lr) * 64 + phys]);
#pragma unroll
                for (int mi = 0; mi < 4; mi++)
#pragma unroll
                    for (int ni = 0; ni < 4; ni++)
                        acc[mi][ni] = __builtin_amdgcn_mfma_f32_16x16x32_bf16(
                            af[mi], bfr[ni], acc[mi][ni], 0, 0, 0);
            }
            __syncthreads();
        }

        // epilogue
#pragma unroll
        for (int mi = 0; mi < 4; mi++) {
#pragma unroll
            for (int r4 = 0; r4 < 4; r4++) {
                const int row = moff + mi * 16 + lq * 4 + r4;
                if (m0 + row < ce) {
                    const int tok = tokrow[row];
                    if (MODE == 0) {
#pragma unroll
                        for (int ni = 0; ni < 4; ni++) {
                            float v = acc[mi][ni][r4];
                            v = v > 0.f ? v : 0.f;
                            Hout[(size_t)tok * FFD + n0 + noff + ni * 16 + lr] = f2bf(v);
                        }
                    } else {
                        const float tp = topp[tok];
#pragma unroll
                        for (int ni = 0; ni < 4; ni++) {
                            const size_t idx = (size_t)tok * DIM + n0 + noff + ni * 16 + lr;
                            out[idx] = hs[idx] + tp * acc[mi][ni][r4];
                        }
                    }
                }
            }
        }
    }
}

// ---------------------------------------------------------------------------
// Fallback (R0-proven) GEMM2 with in-kernel f32->bf16 conversion, used only
// when ws_size is too small to hold pre-converted wo.
// ---------------------------------------------------------------------------
__global__ __launch_bounds__(256) void k_ffn2_old(
    const unsigned short* __restrict__ Hb, const float* __restrict__ wo,
    const int* __restrict__ list, const int* __restrict__ cnt,
    const float* __restrict__ hs, const float* __restrict__ topp,
    float* __restrict__ out)
{
    __shared__ unsigned short Asmo[64][72];
    __shared__ unsigned short Bsmo[64][72];
    __shared__ int tokrow[64];
    __shared__ int spref[9];

    const int t = threadIdx.x;
    const int lane = t & 63, wid = t >> 6;
    if (t == 0) {
        int p = 0; spref[0] = 0;
        for (int e = 0; e < 8; e++) { p += (cnt[e] + 63) >> 6; spref[e + 1] = p; }
    }
    __syncthreads();
    const int TN = DIM / 64;
    const int total = spref[8] * TN;
    const int moff = (wid >> 1) * 32, noff = (wid & 1) * 32;
    const int lr = lane & 15, lk = (lane >> 4) * 8, lq = lane >> 4;
    const int row = t >> 2, kc = (t & 3) << 4;

    for (int w = blockIdx.x; w < total; w += gridDim.x) {
        const int gm = w / TN, tn = w - gm * TN;
        int e = 0;
        while (gm >= spref[e + 1]) e++;
        const int ce = cnt[e];
        const int m0 = (gm - spref[e]) * 64, n0 = tn * 64;

        __syncthreads();
        if (t < 64) { int m = m0 + t; tokrow[t] = (m < ce) ? list[e * N_TOK + m] : -1; }
        __syncthreads();

        f32x4 acc00 = {0,0,0,0}, acc01 = {0,0,0,0}, acc10 = {0,0,0,0}, acc11 = {0,0,0,0};

        for (int k0 = 0; k0 < FFD; k0 += 64) {
            int tok = tokrow[row];
            uint4 q0 = {0,0,0,0}, q1 = {0,0,0,0};
            if (tok >= 0) {
                const uint4* p = (const uint4*)(Hb + (size_t)tok * FFD + k0 + kc);
                q0 = p[0]; q1 = p[1];
            }
            *(uint4*)&Asmo[row][kc]     = q0;
            *(uint4*)&Asmo[row][kc + 8] = q1;
            const float* wp = wo + ((size_t)e * FFD + k0 + row) * DIM + n0 + kc;
#pragma unroll
            for (int j = 0; j < 16; j += 4) {
                float4 f = *(const float4*)(wp + j);
                Bsmo[kc + j + 0][row] = f2bf(f.x);
                Bsmo[kc + j + 1][row] = f2bf(f.y);
                Bsmo[kc + j + 2][row] = f2bf(f.z);
                Bsmo[kc + j + 3][row] = f2bf(f.w);
            }
            __syncthreads();
#pragma unroll
            for (int kf = 0; kf < 2; kf++) {
                bf16x8 a0 = as_bf(*(const u16x8*)&Asmo[moff + lr][kf * 32 + lk]);
                bf16x8 a1 = as_bf(*(const u16x8*)&Asmo[moff + 16 + lr][kf * 32 + lk]);
                bf16x8 b0 = as_bf(*(const u16x8*)&Bsmo[noff + lr][kf * 32 + lk]);
                bf16x8 b1 = as_bf(*(const u16x8*)&Bsmo[noff + 16 + lr][kf * 32 + lk]);
                acc00 = __builtin_amdgcn_mfma_f32_16x16x32_bf16(a0, b0, acc00, 0, 0, 0);
                acc01 = __builtin_amdgcn_mfma_f32_16x16x32_bf16(a0, b1, acc01, 0, 0, 0);
                acc10 = __builtin_amdgcn_mfma_f32_16x16x32_bf16(a1, b0, acc10, 0, 0, 0);
                acc11 = __builtin_amdgcn_mfma_f32_16x16x32_bf16(a1, b1, acc11, 0, 0, 0);
            }
            __syncthreads();
        }
#pragma unroll
        for (int mi = 0; mi < 2; mi++) {
#pragma unroll
            for (int ni = 0; ni < 2; ni++) {
                f32x4 a = (mi == 0) ? ((ni == 0) ? acc00 : acc01)
                                    : ((ni == 0) ? acc10 : acc11);
#pragma unroll
                for (int r = 0; r < 4; r++) {
                    int rr = moff + mi * 16 + lq * 4 + r;
                    int tok = tokrow[rr];
                    if (tok >= 0) {
                        int col = n0 + noff + ni * 16 + lr;
                        size_t idx = (size_t)tok * DIM + col;
                        out[idx] = hs[idx] + topp[tok] * a[r];
                    }
                }
            }
        }
    }
}

// ---------------------------------------------------------------------------
extern "C" void kernel_launch(void* const* d_in, const int* in_sizes, int n_in,
                              void* d_out, int out_size, void* d_ws, size_t ws_size,
                              hipStream_t stream)
{
    const float* hs  = (const float*)d_in[0];
    const float* lnw = (const float*)d_in[1];
    const float* rw  = (const float*)d_in[2];
    const float* wi  = (const float*)d_in[3];
    const float* wo  = (const float*)d_in[4];

    float* out        = (float*)d_out;
    float* out_logits = out + (size_t)N_TOK * DIM;
    float* out_eidx   = out_logits + (size_t)N_TOK * NEXP;

    char* ws = (char*)d_ws;
    size_t off = 0;
    int*   cnt  = (int*)(ws + off);            off += 256;
    int*   list = (int*)(ws + off);            off += (size_t)NEXP * N_TOK * 4;
    float* topp = (float*)(ws + off);          off += (size_t)N_TOK * 4;
    unsigned short* xn  = (unsigned short*)(ws + off); off += (size_t)N_TOK * DIM * 2;
    unsigned short* Hb  = (unsigned short*)(ws + off); off += (size_t)N_TOK * FFD * 2;
    unsigned short* wob = (unsigned short*)(ws + off);
    const size_t need = off + (size_t)NEXP * FFD * DIM * 2;
    const bool pre2 = (ws_size >= need);

    // wi^T (bf16 [e][F][D]) lives in the d_out scratch region: it is dead by
    // the time GEMM2's epilogue writes `out`, and fits (37.75 MB < 50.3 MB).
    unsigned short* wib = (unsigned short*)d_out;

    hipMemsetAsync(cnt, 0, NEXP * sizeof(int), stream);
    k_convT<<<NEXP * (DIM / 64) * (FFD / 64), 256, 0, stream>>>(wi, wib, DIM, FFD);
    k_router<<<N_TOK / 4, 256, 0, stream>>>(hs, lnw, rw, out_logits, out_eidx,
                                            topp, list, cnt, xn);
    k_gemm<0><<<3264, 256, 0, stream>>>(xn, wib, list, cnt, Hb,
                                        nullptr, nullptr, nullptr);
    if (pre2) {
        k_convT<<<NEXP * (FFD / 64) * (DIM / 64), 256, 0, stream>>>(wo, wob, FFD, DIM);
        k_gemm<1><<<816, 256, 0, stream>>>(Hb, wob, list, cnt, nullptr,
                                           hs, topp, out);
    } else {
        k_ffn2_old<<<3156, 256, 0, stream>>>(Hb, wo, list, cnt, hs, topp, out);
    }
}

// Round 3
// 385.950 us; speedup vs baseline: 1.8593x; 1.3544x over previous
//
#include <hip/hip_runtime.h>
#include <math.h>

#define N_TOK 16384
#define DIM   768
#define FFD   3072
#define NEXP  8
#define EPSV  1e-6f

typedef __attribute__((ext_vector_type(4))) float f32x4;
typedef __attribute__((ext_vector_type(4))) unsigned short u16x4;
typedef __attribute__((ext_vector_type(8))) unsigned short u16x8;
typedef __attribute__((ext_vector_type(8))) __bf16 bf16x8;

static __device__ __forceinline__ unsigned short f2bf(float f) {
    unsigned int u = __builtin_bit_cast(unsigned int, f);
    u += 0x7fffu + ((u >> 16) & 1u);   // round-to-nearest-even
    return (unsigned short)(u >> 16);
}
static __device__ __forceinline__ bf16x8 as_bf(u16x8 v) {
    return __builtin_bit_cast(bf16x8, v);
}
static __device__ __forceinline__ void gload16(const void* g, void* l) {
    __builtin_amdgcn_global_load_lds(
        (const __attribute__((address_space(1))) unsigned int*)g,
        (__attribute__((address_space(3))) unsigned int*)l, 16, 0, 0);
}

// ---------------------------------------------------------------------------
// Kernel 0: convert+transpose  in[e][R][C] f32  ->  out[e][C][R] bf16
// ---------------------------------------------------------------------------
__global__ __launch_bounds__(256) void k_convT(
    const float* __restrict__ in, unsigned short* __restrict__ outp,
    int R, int C)
{
    __shared__ float tile[64][68];
    const int bc = C >> 6, br = R >> 6;
    const int b = blockIdx.x;
    const int e = b / (bc * br);
    const int rem = b - e * bc * br;
    const int rt = rem / bc, ct = rem - rt * bc;
    const int t = threadIdx.x;
    {
        const int r = t >> 2, c4 = (t & 3) << 4;
        const float* src = in + ((size_t)e * R + rt * 64 + r) * C + ct * 64 + c4;
#pragma unroll
        for (int q = 0; q < 4; q++) {
            float4 f = ((const float4*)src)[q];
            tile[r][c4 + q * 4 + 0] = f.x;
            tile[r][c4 + q * 4 + 1] = f.y;
            tile[r][c4 + q * 4 + 2] = f.z;
            tile[r][c4 + q * 4 + 3] = f.w;
        }
    }
    __syncthreads();
    {
        const int c = t >> 2, r4 = (t & 3) << 4;
        u16x8 o0, o1;
#pragma unroll
        for (int j = 0; j < 8; j++)  o0[j] = f2bf(tile[r4 + j][c]);
#pragma unroll
        for (int j = 0; j < 8; j++)  o1[j] = f2bf(tile[r4 + 8 + j][c]);
        unsigned short* dst = outp + ((size_t)e * C + ct * 64 + c) * R + rt * 64 + r4;
        *(u16x8*)dst       = o0;
        *(u16x8*)(dst + 8) = o1;
    }
}

// ---------------------------------------------------------------------------
// Kernel 1: RMSNorm + router, one wave per token. NO global atomics.
// ---------------------------------------------------------------------------
__global__ __launch_bounds__(256) void k_router(
    const float* __restrict__ x, const float* __restrict__ lnw,
    const float* __restrict__ rw,
    float* __restrict__ out_logits, float* __restrict__ out_eidx,
    float* __restrict__ topp, int* __restrict__ eidx,
    unsigned short* __restrict__ xn)
{
    const int wid = threadIdx.x >> 6, lane = threadIdx.x & 63;
    const int tok = blockIdx.x * 4 + wid;
    const size_t base = (size_t)tok * DIM;

    float4 v[3];
#pragma unroll
    for (int j = 0; j < 3; j++)
        v[j] = *(const float4*)(x + base + lane * 4 + j * 256);
    float ss = 0.f;
#pragma unroll
    for (int j = 0; j < 3; j++)
        ss += v[j].x * v[j].x + v[j].y * v[j].y + v[j].z * v[j].z + v[j].w * v[j].w;
#pragma unroll
    for (int s = 32; s > 0; s >>= 1) ss += __shfl_xor(ss, s);
    const float rstd = rsqrtf(ss * (1.0f / DIM) + EPSV);

    float rp[8];
#pragma unroll
    for (int e = 0; e < 8; e++) rp[e] = 0.f;
#pragma unroll
    for (int j = 0; j < 3; j++) {
        float4 lw = *(const float4*)(lnw + lane * 4 + j * 256);
        float xv[4] = { v[j].x * rstd * lw.x, v[j].y * rstd * lw.y,
                        v[j].z * rstd * lw.z, v[j].w * rstd * lw.w };
        u16x4 pk = { f2bf(xv[0]), f2bf(xv[1]), f2bf(xv[2]), f2bf(xv[3]) };
        *(u16x4*)(xn + base + lane * 4 + j * 256) = pk;
#pragma unroll
        for (int i = 0; i < 4; i++) {
            const int d = lane * 4 + j * 256 + i;
            const float4* rr = (const float4*)(rw + (size_t)d * 8);
            float4 a = rr[0], bq = rr[1];
            rp[0] += xv[i] * a.x;  rp[1] += xv[i] * a.y;
            rp[2] += xv[i] * a.z;  rp[3] += xv[i] * a.w;
            rp[4] += xv[i] * bq.x; rp[5] += xv[i] * bq.y;
            rp[6] += xv[i] * bq.z; rp[7] += xv[i] * bq.w;
        }
    }
#pragma unroll
    for (int s = 32; s > 0; s >>= 1) {
#pragma unroll
        for (int e = 0; e < 8; e++) rp[e] += __shfl_xor(rp[e], s);
    }
    if (lane == 0) {
        float m = -1e30f; int am = 0;
#pragma unroll
        for (int e = 0; e < 8; e++) {
            out_logits[(size_t)tok * 8 + e] = rp[e];
            if (rp[e] > m) { m = rp[e]; am = e; }
        }
        float se = 0.f;
#pragma unroll
        for (int e = 0; e < 8; e++) se += expf(rp[e] - m);
        topp[tok] = 1.0f / se;
        out_eidx[tok] = (float)am;
        eidx[tok] = am;
    }
}

// ---------------------------------------------------------------------------
// Kernel 2a: per-block expert histogram (64 blocks x 256 tokens).
// ---------------------------------------------------------------------------
__global__ __launch_bounds__(256) void k_hist(
    const int* __restrict__ eidx, int* __restrict__ blkhist)
{
    __shared__ int h[8];
    if (threadIdx.x < 8) h[threadIdx.x] = 0;
    __syncthreads();
    atomicAdd(&h[eidx[blockIdx.x * 256 + threadIdx.x]], 1);
    __syncthreads();
    if (threadIdx.x < 8) blkhist[blockIdx.x * 8 + threadIdx.x] = h[threadIdx.x];
}

// ---------------------------------------------------------------------------
// Kernel 2b: deterministic stable counting-sort scatter -> dense list + cnt.
// ---------------------------------------------------------------------------
__global__ __launch_bounds__(256) void k_scatter(
    const int* __restrict__ eidx, const int* __restrict__ blkhist,
    int* __restrict__ list, int* __restrict__ cnt)
{
    __shared__ int bh[64 * 8];
    __shared__ int wcnt[4][8];
    const int t = threadIdx.x, b = blockIdx.x;
    const int lane = t & 63, wid = t >> 6;
    bh[t] = blkhist[t];
    bh[t + 256] = blkhist[t + 256];
    __syncthreads();
    const int tok = b * 256 + t;
    const int e = eidx[tok];
    int ebase = 0, bbase = 0, tot[8];
#pragma unroll
    for (int q = 0; q < 8; q++) {
        int sa = 0, sp = 0;
        for (int bb = 0; bb < 64; bb++) {
            int v = bh[bb * 8 + q];
            sa += v;
            if (bb < b) sp += v;
        }
        tot[q] = sa;
        if (q < e) ebase += sa;
        if (q == e) bbase = sp;
    }
    int wrank = 0;
#pragma unroll
    for (int q = 0; q < 8; q++) {
        unsigned long long m = __ballot(e == q);
        if (e == q) wrank = __popcll(m & ((1ull << lane) - 1ull));
        if (lane == 0) wcnt[wid][q] = __popcll(m);
    }
    __syncthreads();
    int wbase = 0;
#pragma unroll
    for (int w = 0; w < 4; w++)
        if (w < wid) wbase += wcnt[w][e];
    list[ebase + bbase + wbase + wrank] = tok;
    if (b == 0 && t < 8) cnt[t] = tot[t];
}

// ---------------------------------------------------------------------------
// Grouped GEMM: 128x256 tile, BK=64, 4 waves (each 64x128), global_load_lds,
// XOR chunk swizzle, bijective XCD swizzle on tile index.
// MODE 0: H = relu(Xn @ WiT)   MODE 1: out = hs + topp*(H @ WoT)
// ---------------------------------------------------------------------------
template<int MODE>
__global__ __launch_bounds__(256, 2) void k_gemm(
    const unsigned short* __restrict__ A, const unsigned short* __restrict__ Bw,
    const int* __restrict__ list, const int* __restrict__ cnt,
    unsigned short* __restrict__ Hout,
    const float* __restrict__ hs, const float* __restrict__ topp,
    float* __restrict__ out)
{
    constexpr int K   = (MODE == 0) ? DIM : FFD;
    constexpr int N   = (MODE == 0) ? FFD : DIM;
    constexpr int TNT = N / 256;                  // 12 / 3
    __shared__ unsigned short Asm[128 * 64];      // 16 KB
    __shared__ unsigned short Bsm[256 * 64];      // 32 KB
    __shared__ int tokrow[128];
    __shared__ int spref[9];
    __shared__ int ebase[8];

    const int t = threadIdx.x, lane = t & 63, wid = t >> 6;
    if (t == 0) {
        int p = 0, qq = 0;
        spref[0] = 0;
#pragma unroll
        for (int e = 0; e < 8; e++) {
            ebase[e] = qq; qq += cnt[e];
            p += (cnt[e] + 127) >> 7;
            spref[e + 1] = p;
        }
    }
    __syncthreads();
    const int total = spref[8] * TNT;
    const int moff = (wid >> 1) * 64, noff = (wid & 1) * 128;
    const int lr = lane & 15, lq = lane >> 4;

    // bijective XCD swizzle (m204): consecutive tiles -> same XCD
    const int nwg = gridDim.x;
    const int xcd = blockIdx.x & 7, rr8 = blockIdx.x >> 3;
    const int qd = nwg >> 3, rm = nwg & 7;
    const int bid = (xcd < rm ? xcd * (qd + 1) : rm * (qd + 1) + (xcd - rm) * qd) + rr8;

    // staging chunk geometry (chunk = 16B): A 1024 chunks, B 2048 chunks
    int arow[4], asub[4], brow[8], bsub[8];
#pragma unroll
    for (int i = 0; i < 4; i++) {
        int c = (wid * 4 + i) * 64 + lane;
        arow[i] = c >> 3;
        asub[i] = (c & 7) ^ (arow[i] & 7);
    }
#pragma unroll
    for (int i = 0; i < 8; i++) {
        int c = (wid * 8 + i) * 64 + lane;
        brow[i] = c >> 3;
        bsub[i] = (c & 7) ^ (brow[i] & 7);
    }

    for (int w = bid; w < total; w += gridDim.x) {
        const int gm = w / TNT, tn = w - gm * TNT;
        int e = 0;
        while (gm >= spref[e + 1]) e++;
        const int ce = cnt[e], eb = ebase[e];
        const int m0 = (gm - spref[e]) * 128, n0 = tn * 256;

        __syncthreads();
        if (t < 128)
            tokrow[t] = (m0 + t < ce) ? list[eb + m0 + t] : list[eb];
        __syncthreads();

        const unsigned short* aP[4];
        const unsigned short* bP[8];
#pragma unroll
        for (int i = 0; i < 4; i++)
            aP[i] = A + (size_t)tokrow[arow[i]] * K + asub[i] * 8;
#pragma unroll
        for (int i = 0; i < 8; i++)
            bP[i] = Bw + ((size_t)e * N + n0 + brow[i]) * K + bsub[i] * 8;

        f32x4 acc[4][8];
#pragma unroll
        for (int mi = 0; mi < 4; mi++)
#pragma unroll
            for (int ni = 0; ni < 8; ni++) acc[mi][ni] = (f32x4){0, 0, 0, 0};

        for (int k0 = 0; k0 < K; k0 += 64) {
#pragma unroll
            for (int i = 0; i < 4; i++)
                gload16(aP[i] + k0, Asm + (wid * 4 + i) * 512);
#pragma unroll
            for (int i = 0; i < 8; i++)
                gload16(bP[i] + k0, Bsm + (wid * 8 + i) * 512);
            __syncthreads();
#pragma unroll
            for (int kf = 0; kf < 2; kf++) {
                const int phys = ((kf * 4 + lq) ^ (lr & 7)) * 8;
                bf16x8 af[4], bfr[8];
#pragma unroll
                for (int mi = 0; mi < 4; mi++)
                    af[mi] = as_bf(*(const u16x8*)&Asm[(moff + mi * 16 + lr) * 64 + phys]);
#pragma unroll
                for (int ni = 0; ni < 8; ni++)
                    bfr[ni] = as_bf(*(const u16x8*)&Bsm[(noff + ni * 16 + lr) * 64 + phys]);
#pragma unroll
                for (int mi = 0; mi < 4; mi++)
#pragma unroll
                    for (int ni = 0; ni < 8; ni++)
                        acc[mi][ni] = __builtin_amdgcn_mfma_f32_16x16x32_bf16(
                            af[mi], bfr[ni], acc[mi][ni], 0, 0, 0);
            }
            __syncthreads();
        }

#pragma unroll
        for (int mi = 0; mi < 4; mi++) {
#pragma unroll
            for (int r4 = 0; r4 < 4; r4++) {
                const int row = moff + mi * 16 + lq * 4 + r4;
                if (m0 + row < ce) {
                    const int tok = tokrow[row];
                    if (MODE == 0) {
#pragma unroll
                        for (int ni = 0; ni < 8; ni++) {
                            float v = acc[mi][ni][r4];
                            v = v > 0.f ? v : 0.f;
                            Hout[(size_t)tok * FFD + n0 + noff + ni * 16 + lr] = f2bf(v);
                        }
                    } else {
                        const float tp = topp[tok];
#pragma unroll
                        for (int ni = 0; ni < 8; ni++) {
                            const size_t idx = (size_t)tok * DIM + n0 + noff + ni * 16 + lr;
                            out[idx] = hs[idx] + tp * acc[mi][ni][r4];
                        }
                    }
                }
            }
        }
    }
}

// ---------------------------------------------------------------------------
// Fallback GEMM2 (in-kernel f32->bf16 convert), dense-list version. Used only
// if ws cannot hold pre-converted wo.
// ---------------------------------------------------------------------------
__global__ __launch_bounds__(256) void k_ffn2_old(
    const unsigned short* __restrict__ Hb, const float* __restrict__ wo,
    const int* __restrict__ list, const int* __restrict__ cnt,
    const float* __restrict__ hs, const float* __restrict__ topp,
    float* __restrict__ out)
{
    __shared__ unsigned short Asmo[64][72];
    __shared__ unsigned short Bsmo[64][72];
    __shared__ int tokrow[64];
    __shared__ int spref[9];
    __shared__ int ebase[8];

    const int t = threadIdx.x;
    const int lane = t & 63, wid = t >> 6;
    if (t == 0) {
        int p = 0, qq = 0; spref[0] = 0;
        for (int e = 0; e < 8; e++) {
            ebase[e] = qq; qq += cnt[e];
            p += (cnt[e] + 63) >> 6; spref[e + 1] = p;
        }
    }
    __syncthreads();
    const int TN = DIM / 64;
    const int total = spref[8] * TN;
    const int moff = (wid >> 1) * 32, noff = (wid & 1) * 32;
    const int lr = lane & 15, lk = (lane >> 4) * 8, lq = lane >> 4;
    const int row = t >> 2, kc = (t & 3) << 4;

    for (int w = blockIdx.x; w < total; w += gridDim.x) {
        const int gm = w / TN, tn = w - gm * TN;
        int e = 0;
        while (gm >= spref[e + 1]) e++;
        const int ce = cnt[e];
        const int m0 = (gm - spref[e]) * 64, n0 = tn * 64;

        __syncthreads();
        if (t < 64) { int m = m0 + t; tokrow[t] = (m < ce) ? list[ebase[e] + m] : -1; }
        __syncthreads();

        f32x4 acc00 = {0,0,0,0}, acc01 = {0,0,0,0}, acc10 = {0,0,0,0}, acc11 = {0,0,0,0};

        for (int k0 = 0; k0 < FFD; k0 += 64) {
            int tok = tokrow[row];
            uint4 q0 = {0,0,0,0}, q1 = {0,0,0,0};
            if (tok >= 0) {
                const uint4* p = (const uint4*)(Hb + (size_t)tok * FFD + k0 + kc);
                q0 = p[0]; q1 = p[1];
            }
            *(uint4*)&Asmo[row][kc]     = q0;
            *(uint4*)&Asmo[row][kc + 8] = q1;
            const float* wp = wo + ((size_t)e * FFD + k0 + row) * DIM + n0 + kc;
#pragma unroll
            for (int j = 0; j < 16; j += 4) {
                float4 f = *(const float4*)(wp + j);
                Bsmo[kc + j + 0][row] = f2bf(f.x);
                Bsmo[kc + j + 1][row] = f2bf(f.y);
                Bsmo[kc + j + 2][row] = f2bf(f.z);
                Bsmo[kc + j + 3][row] = f2bf(f.w);
            }
            __syncthreads();
#pragma unroll
            for (int kf = 0; kf < 2; kf++) {
                bf16x8 a0 = as_bf(*(const u16x8*)&Asmo[moff + lr][kf * 32 + lk]);
                bf16x8 a1 = as_bf(*(const u16x8*)&Asmo[moff + 16 + lr][kf * 32 + lk]);
                bf16x8 b0 = as_bf(*(const u16x8*)&Bsmo[noff + lr][kf * 32 + lk]);
                bf16x8 b1 = as_bf(*(const u16x8*)&Bsmo[noff + 16 + lr][kf * 32 + lk]);
                acc00 = __builtin_amdgcn_mfma_f32_16x16x32_bf16(a0, b0, acc00, 0, 0, 0);
                acc01 = __builtin_amdgcn_mfma_f32_16x16x32_bf16(a0, b1, acc01, 0, 0, 0);
                acc10 = __builtin_amdgcn_mfma_f32_16x16x32_bf16(a1, b0, acc10, 0, 0, 0);
                acc11 = __builtin_amdgcn_mfma_f32_16x16x32_bf16(a1, b1, acc11, 0, 0, 0);
            }
            __syncthreads();
        }
#pragma unroll
        for (int mi = 0; mi < 2; mi++) {
#pragma unroll
            for (int ni = 0; ni < 2; ni++) {
                f32x4 a = (mi == 0) ? ((ni == 0) ? acc00 : acc01)
                                    : ((ni == 0) ? acc10 : acc11);
#pragma unroll
                for (int r = 0; r < 4; r++) {
                    int rr = moff + mi * 16 + lq * 4 + r;
                    int tok = tokrow[rr];
                    if (tok >= 0) {
                        int col = n0 + noff + ni * 16 + lr;
                        size_t idx = (size_t)tok * DIM + col;
                        out[idx] = hs[idx] + topp[tok] * a[r];
                    }
                }
            }
        }
    }
}

// ---------------------------------------------------------------------------
extern "C" void kernel_launch(void* const* d_in, const int* in_sizes, int n_in,
                              void* d_out, int out_size, void* d_ws, size_t ws_size,
                              hipStream_t stream)
{
    const float* hs  = (const float*)d_in[0];
    const float* lnw = (const float*)d_in[1];
    const float* rw  = (const float*)d_in[2];
    const float* wi  = (const float*)d_in[3];
    const float* wo  = (const float*)d_in[4];

    float* out        = (float*)d_out;
    float* out_logits = out + (size_t)N_TOK * DIM;
    float* out_eidx   = out_logits + (size_t)N_TOK * NEXP;

    char* ws = (char*)d_ws;
    size_t off = 0;
    int*   cnt     = (int*)(ws + off);         off += 256;
    int*   list    = (int*)(ws + off);         off += (size_t)N_TOK * 4;
    float* topp    = (float*)(ws + off);       off += (size_t)N_TOK * 4;
    int*   eidx    = (int*)(ws + off);         off += (size_t)N_TOK * 4;
    int*   blkhist = (int*)(ws + off);         off += 4096;
    unsigned short* xn  = (unsigned short*)(ws + off); off += (size_t)N_TOK * DIM * 2;
    unsigned short* Hb  = (unsigned short*)(ws + off); off += (size_t)N_TOK * FFD * 2;
    unsigned short* wob = (unsigned short*)(ws + off);
    const size_t need = off + (size_t)NEXP * FFD * DIM * 2;
    const bool pre2 = (ws_size >= need);

    // wi^T (bf16 [e][F][D]) lives in d_out's first 37.75 MB: dead before
    // GEMM2's epilogue writes `out`, and smaller than the 48 MB out region.
    unsigned short* wib = (unsigned short*)d_out;

    k_convT<<<NEXP * (DIM / 64) * (FFD / 64), 256, 0, stream>>>(wi, wib, DIM, FFD);
    k_router<<<N_TOK / 4, 256, 0, stream>>>(hs, lnw, rw, out_logits, out_eidx,
                                            topp, eidx, xn);
    k_hist<<<64, 256, 0, stream>>>(eidx, blkhist);
    k_scatter<<<64, 256, 0, stream>>>(eidx, blkhist, list, cnt);
    k_gemm<0><<<1632, 256, 0, stream>>>(xn, wib, list, cnt, Hb,
                                        nullptr, nullptr, nullptr);
    if (pre2) {
        k_convT<<<NEXP * (FFD / 64) * (DIM / 64), 256, 0, stream>>>(wo, wob, FFD, DIM);
        k_gemm<1><<<408, 256, 0, stream>>>(Hb, wob, list, cnt, nullptr,
                                           hs, topp, out);
    } else {
        k_ffn2_old<<<3156, 256, 0, stream>>>(Hb, wo, list, cnt, hs, topp, out);
    }
}